// Round 11
// baseline (22.462 us; speedup 1.0000x reference)
//
#include <hip/hip_runtime.h>

// Problem constants
#define BATCH 2048
#define IN    512
#define OUT   512
#define NG    8
#define KTOT  1024   // concatenated K: [S | silu] x [Cw | w_b]

// GEMM: 64x64 tile, BK=64, split-K x2 (512 blocks = 2 blocks/CU).
// Linear row-major ws [row][KTOT]; both-sides XOR swizzle via pre-swizzled
// global source for gload_lds (linear LDS dest) + swizzled ds_read.
#define TILE_SHORTS 4096       // 64*64
#define NITH 8                 // K-iters per K-half

typedef __attribute__((ext_vector_type(8))) short bf16x8;
typedef __attribute__((ext_vector_type(4))) float f32x4;

__device__ inline unsigned short f2bf(float f) {
    union { float f; unsigned int u; } v; v.f = f;
    unsigned int r = v.u + 0x7fffu + ((v.u >> 16) & 1u);
    return (unsigned short)(r >> 16);
}

__device__ inline void gload_lds16(const void* g, void* l) {
    __builtin_amdgcn_global_load_lds((const __attribute__((address_space(1))) void*)g,
                                     (__attribute__((address_space(3))) void*)l, 16, 0, 0);
}

// ---------------------------------------------------------------------------
// Fused prep (round-4 verbatim): blocks [0,512) build A', [512,640) build B'.
//   A'[b][i] = sum_n exp(-(x[b,i]-g_n)^2)   A'[b][512+i] = silu(x[b,i])
//   B'[o][i] = (sum_a c[a,o,i]) * w_s[o,i]  B'[o][512+i] = w_b[o,i]
// Spline via uniform-grid factorization: 3 exp + Horner instead of 9 exp.
// ---------------------------------------------------------------------------
__global__ __launch_bounds__(256) void prep_kernel(const float* __restrict__ x,
                                                   const float* __restrict__ c,
                                                   const float* __restrict__ w_b,
                                                   const float* __restrict__ w_s,
                                                   const float* __restrict__ grid,
                                                   unsigned short* __restrict__ A,
                                                   unsigned short* __restrict__ B) {
    int blk = blockIdx.x;
    int tid = threadIdx.x;
    if (blk < 512) {
        int e = (blk * 256 + tid) * 8;       // element base in x (row-aligned)
        float g0 = grid[0];
        float dl = grid[1] - g0;             // uniform spacing (4/7)
        float d2 = dl * dl;
        float dn[NG];
#pragma unroll
        for (int n = 0; n < NG; ++n) dn[n] = __expf(-d2 * (float)(n * n));
        float4 x0 = *(const float4*)&x[e];
        float4 x1 = *(const float4*)&x[e + 4];
        float xv[8] = {x0.x, x0.y, x0.z, x0.w, x1.x, x1.y, x1.z, x1.w};
        unsigned short sv[8], lv[8];
#pragma unroll
        for (int j = 0; j < 8; ++j) {
            float u  = xv[j] - g0;
            float e1 = __expf(-u * u);
            float q  = __expf(2.f * dl * u);
            float p  = dn[NG - 1];
#pragma unroll
            for (int n = NG - 2; n >= 0; --n) p = p * q + dn[n];
            sv[j] = f2bf(e1 * p);
            lv[j] = f2bf(xv[j] / (1.f + __expf(-xv[j])));
        }
        int b = e >> 9, i = e & 511;
        *(int4*)&A[b * KTOT + i]       = *(int4*)sv;
        *(int4*)&A[b * KTOT + 512 + i] = *(int4*)lv;
    } else {
        int e = ((blk - 512) * 256 + tid) * 8;
        float acc[8] = {};
#pragma unroll
        for (int a = 0; a < NG; ++a) {
            float4 c0 = *(const float4*)&c[(size_t)a * (OUT * IN) + e];
            float4 c1 = *(const float4*)&c[(size_t)a * (OUT * IN) + e + 4];
            acc[0] += c0.x; acc[1] += c0.y; acc[2] += c0.z; acc[3] += c0.w;
            acc[4] += c1.x; acc[5] += c1.y; acc[6] += c1.z; acc[7] += c1.w;
        }
        float4 s0 = *(const float4*)&w_s[e];
        float4 s1 = *(const float4*)&w_s[e + 4];
        float sw[8] = {s0.x, s0.y, s0.z, s0.w, s1.x, s1.y, s1.z, s1.w};
        float4 b0 = *(const float4*)&w_b[e];
        float4 b1 = *(const float4*)&w_b[e + 4];
        float bw[8] = {b0.x, b0.y, b0.z, b0.w, b1.x, b1.y, b1.z, b1.w};
        unsigned short cv[8], bv[8];
#pragma unroll
        for (int j = 0; j < 8; ++j) { cv[j] = f2bf(acc[j] * sw[j]); bv[j] = f2bf(bw[j]); }
        int o = e >> 9, i = e & 511;
        *(int4*)&B[o * KTOT + i]       = *(int4*)cv;
        *(int4*)&B[o * KTOT + 512 + i] = *(int4*)bv;
    }
}

// ---------------------------------------------------------------------------
// bf16 MFMA GEMM, split-K x2: P[khalf] = A'[:, khalf*512:+512] * B'^T half.
// 512 blocks (2/CU): tile = bid&255 (XCD decode), khalf = bid>>8
// (bid and bid+256 share bid%8 -> same XCD -> A-strip stays L2-local).
// 512 threads = 8 waves: (wm,wn) 32x32 quadrant, ks = K-slice of 32.
// R10-verified counted-vmcnt 3-buffer pipeline, NITH=8 iters.
// ---------------------------------------------------------------------------
__global__ __launch_bounds__(512, 4) void gemm_kernel(const unsigned short* __restrict__ A,
                                                      const unsigned short* __restrict__ B,
                                                      float* __restrict__ P) {
    __shared__ short As[3][TILE_SHORTS];
    __shared__ short Bs[3][TILE_SHORTS];

    int tid  = threadIdx.x;
    int lane = tid & 63;
    int w    = tid >> 6;               // 0..7
    int wm   = (w >> 2) & 1;
    int wn   = (w >> 1) & 1;
    int ks   = w & 1;                  // K-slice within BK
    int lr   = lane & 15, lg = lane >> 4;

    int bid   = blockIdx.x;
    int tile  = bid & 255;
    int khalf = bid >> 8;
    int mg   = tile & 7;               // XCD id
    int rest = tile >> 3;
    int sub  = rest >> 3;              // 0..3
    int ncol = rest & 7;               // 0..7
    int mt   = mg * 4 + sub;           // 0..31
    int m0   = mt * 64;
    int n0   = ncol * 64;

    // staging: linear LDS dest tid*16B; global source chunk XOR-permuted.
    int srow = tid >> 3;
    int gsc  = (tid & 7) ^ (srow & 7);
    const unsigned short* a_src = A + (size_t)(m0 + srow) * KTOT + khalf * 512 + gsc * 8;
    const unsigned short* b_src = B + (size_t)(n0 + srow) * KTOT + khalf * 512 + gsc * 8;

    // swizzled ds_read chunk: rows congruent to lr mod 8 for all fragments
    int swc  = ((ks * 4 + lg) ^ (lr & 7)) * 8;
    int ra0  = (wm * 32 + lr)      * 64 + swc;
    int ra1  = (wm * 32 + 16 + lr) * 64 + swc;
    int rb0  = (wn * 32 + lr)      * 64 + swc;
    int rb1  = (wn * 32 + 16 + lr) * 64 + swc;

    f32x4 acc00 = {0.f, 0.f, 0.f, 0.f};
    f32x4 acc01 = {0.f, 0.f, 0.f, 0.f};
    f32x4 acc10 = {0.f, 0.f, 0.f, 0.f};
    f32x4 acc11 = {0.f, 0.f, 0.f, 0.f};

    // STAGE(t, buf): stage K-tile t into LDS buffer buf (2 gload_lds16)
#define STAGE(t, buf) do { \
        gload_lds16(a_src + (t) * 64, &As[buf][tid * 8]); \
        gload_lds16(b_src + (t) * 64, &Bs[buf][tid * 8]); \
    } while (0)

    STAGE(0, 0);
    STAGE(1, 1);
    asm volatile("s_waitcnt vmcnt(2)" ::: "memory");
    __builtin_amdgcn_s_barrier();
    __builtin_amdgcn_sched_barrier(0);

#pragma unroll
    for (int it = 0; it < NITH; ++it) {
        int cur = it % 3;
        if (it + 2 < NITH) STAGE(it + 2, (it + 2) % 3);
        bf16x8 a0 = *(const bf16x8*)&As[cur][ra0];
        bf16x8 a1 = *(const bf16x8*)&As[cur][ra1];
        bf16x8 b0 = *(const bf16x8*)&Bs[cur][rb0];
        bf16x8 b1 = *(const bf16x8*)&Bs[cur][rb1];
        acc00 = __builtin_amdgcn_mfma_f32_16x16x32_bf16(a0, b0, acc00, 0, 0, 0);
        acc01 = __builtin_amdgcn_mfma_f32_16x16x32_bf16(a0, b1, acc01, 0, 0, 0);
        acc10 = __builtin_amdgcn_mfma_f32_16x16x32_bf16(a1, b0, acc10, 0, 0, 0);
        acc11 = __builtin_amdgcn_mfma_f32_16x16x32_bf16(a1, b1, acc11, 0, 0, 0);
        if (it + 1 < NITH) {
            if (it + 2 < NITH) asm volatile("s_waitcnt vmcnt(2)" ::: "memory");
            else               asm volatile("s_waitcnt vmcnt(0)" ::: "memory");
            __builtin_amdgcn_s_barrier();
            __builtin_amdgcn_sched_barrier(0);
        }
    }
#undef STAGE

    // cross-ks reduce within block, then store partial to P[khalf]
    __syncthreads();
    float* Ls = (float*)&As[0][0];
    int p = w >> 1;                    // quadrant id 0..3
    if (ks == 1) {
        *(f32x4*)&Ls[p * 1024 + lane * 16 + 0]  = acc00;
        *(f32x4*)&Ls[p * 1024 + lane * 16 + 4]  = acc01;
        *(f32x4*)&Ls[p * 1024 + lane * 16 + 8]  = acc10;
        *(f32x4*)&Ls[p * 1024 + lane * 16 + 12] = acc11;
    }
    __syncthreads();
    if (ks == 0) {
        f32x4 p00 = *(const f32x4*)&Ls[p * 1024 + lane * 16 + 0];
        f32x4 p01 = *(const f32x4*)&Ls[p * 1024 + lane * 16 + 4];
        f32x4 p10 = *(const f32x4*)&Ls[p * 1024 + lane * 16 + 8];
        f32x4 p11 = *(const f32x4*)&Ls[p * 1024 + lane * 16 + 12];
        float* Pq = P + (size_t)khalf * (BATCH * OUT);
        // C/D layout: col = lane&15, row = (lane>>4)*4 + reg   [measured m89/m91]
        int orow = m0 + wm * 32 + lg * 4;
        int ocol = n0 + wn * 32 + lr;
#pragma unroll
        for (int r = 0; r < 4; ++r) {
            Pq[(size_t)(orow + r) * OUT + ocol]           = acc00[r] + p00[r];
            Pq[(size_t)(orow + r) * OUT + ocol + 16]      = acc01[r] + p01[r];
            Pq[(size_t)(orow + 16 + r) * OUT + ocol]      = acc10[r] + p10[r];
            Pq[(size_t)(orow + 16 + r) * OUT + ocol + 16] = acc11[r] + p11[r];
        }
    }
}

// ---------------------------------------------------------------------------
// out = P0 + P1 (deterministic split-K combine). 1M f32, float4 x2 / thread.
// ---------------------------------------------------------------------------
__global__ __launch_bounds__(256) void reduce_kernel(const float* __restrict__ P,
                                                     float* __restrict__ outp) {
    int i = (blockIdx.x * 256 + threadIdx.x) * 8;   // 512 blocks cover 1M exactly
    const float* P1 = P + (size_t)BATCH * OUT;
    float4 a0 = *(const float4*)&P[i];
    float4 a1 = *(const float4*)&P[i + 4];
    float4 b0 = *(const float4*)&P1[i];
    float4 b1 = *(const float4*)&P1[i + 4];
    float4 o0 = make_float4(a0.x + b0.x, a0.y + b0.y, a0.z + b0.z, a0.w + b0.w);
    float4 o1 = make_float4(a1.x + b1.x, a1.y + b1.y, a1.z + b1.z, a1.w + b1.w);
    *(float4*)&outp[i]     = o0;
    *(float4*)&outp[i + 4] = o1;
}

extern "C" void kernel_launch(void* const* d_in, const int* in_sizes, int n_in,
                              void* d_out, int out_size, void* d_ws, size_t ws_size,
                              hipStream_t stream) {
    (void)in_sizes; (void)n_in; (void)out_size; (void)ws_size;
    const float* x    = (const float*)d_in[0];
    const float* c    = (const float*)d_in[1];
    const float* w_b  = (const float*)d_in[2];
    const float* w_s  = (const float*)d_in[3];
    const float* grid = (const float*)d_in[4];
    float* outp = (float*)d_out;

    unsigned short* A = (unsigned short*)d_ws;                     // 4 MiB
    unsigned short* B = A + (size_t)BATCH * KTOT;                  // 1 MiB
    float* P = (float*)((char*)d_ws + (8u << 20));                 // 8 MiB partials

    prep_kernel<<<512 + 128, 256, 0, stream>>>(x, c, w_b, w_s, grid, A, B);
    gemm_kernel<<<512, 512, 0, stream>>>(A, B, P);
    reduce_kernel<<<512, 256, 0, stream>>>(P, outp);
}